// Round 9
// baseline (66.160 us; speedup 1.0000x reference)
//
#include <hip/hip_runtime.h>

#define BATCH 4096
#define IN_DIM 512
#define H1DIM 128
#define H2DIM 64
#define DDIM 64
#define NFUNC 2081
#define NFPAD 2112
#define CHUNK 704           // 2112 = 3 * 704
#define KS_PER_CHUNK 22     // 704/32

typedef short bf16x8 __attribute__((ext_vector_type(8)));
typedef float f32x4 __attribute__((ext_vector_type(4)));
#define MFMA(a,b,c) __builtin_amdgcn_mfma_f32_16x16x32_bf16(a,b,c,0,0,0)

#define WSZ1 (H1DIM*IN_DIM)
#define WSZ2 (H2DIM*H1DIM)
#define WSZ3 (DDIM*H2DIM)
#define WSZ4 (H2DIM*DDIM)
#define WSZ5 (H1DIM*H2DIM)
#define WSZ6 (IN_DIM*H1DIM)

__device__ __forceinline__ short f2b(float f) {
    union { float f; unsigned u; } x; x.f = f;
    unsigned r = x.u + 0x7fffu + ((x.u >> 16) & 1u);
    return (short)(r >> 16);
}
__device__ __forceinline__ float b2f(short s) {
    union { unsigned u; float f; } x; x.u = ((unsigned)(unsigned short)s) << 16;
    return x.f;
}
__device__ __forceinline__ void split3f(float v, short& s0, short& s1, short& s2) {
    s0 = f2b(v); float r = v - b2f(s0);
    s1 = f2b(r); float r2 = r - b2f(s1);
    s2 = f2b(r2);
}
__device__ __forceinline__ uint2 pk4(const short* s) {
    union { short s[4]; uint2 u; } z;
    z.s[0] = s[0]; z.s[1] = s[1]; z.s[2] = s[2]; z.s[3] = s[3];
    return z.u;
}

// counted wait on our own DMA queue; older entries (bias/stores) retire first
template<int N> __device__ __forceinline__ void waitv() {
    asm volatile("s_waitcnt vmcnt(%0)" :: "n"(N) : "memory");
    __builtin_amdgcn_sched_barrier(0);
}

// ---- swizzled LDS tile helpers (row stride RS shorts, byte ^= (r&7)<<4) ----
__device__ __forceinline__ void st_b16(short* t, int RS, int r, int c, short v) {
    int b = (c * 2) ^ ((r & 7) << 4);
    *(short*)((char*)(t + r * RS) + b) = v;
}
__device__ __forceinline__ void st_b64(short* t, int RS, int r, int c0, uint2 v) {
    int b = (c0 * 2) ^ ((r & 7) << 4);
    *(uint2*)((char*)(t + r * RS) + b) = v;
}
__device__ __forceinline__ bf16x8 ld_af(const short* t, int RS, int lane, int kbase) {
    int r = lane & 15;
    int b = ((kbase + (lane >> 4) * 8) * 2) ^ ((r & 7) << 4);
    return *(const bf16x8*)((const char*)(t + r * RS) + b);
}
// packed-frag global load (plain compiler load; used in small segments)
__device__ __forceinline__ bf16x8 ld_bp(const short* P, int blk, int lane) {
    return *(const bf16x8*)(P + ((size_t)blk * 64 + lane) * 8);
}

// 9-MFMA split-precision dual step (order identical to r8 -> same numerics)
__device__ __forceinline__ void mf9(bf16x8 f0, bf16x8 f1, bf16x8 f2, bf16x8 fv,
                                    bf16x8 b0, bf16x8 b1, bf16x8 b2,
                                    f32x4& P, f32x4& Q, f32x4& V) {
    P = MFMA(f0, b0, P); Q = MFMA(f1, b1, Q);
    P = MFMA(f1, b0, P); Q = MFMA(f0, b1, Q);
    P = MFMA(f2, b0, P); Q = MFMA(f2, b1, Q);
    P = MFMA(f0, b2, P); Q = MFMA(f1, b2, Q);
    V = MFMA(fv, b0, V);
}

__device__ __forceinline__ void epi_store(short* t0, short* t1, short* t2, short* tv, int RS,
                                          int lane, int col, const f32x4& P, const f32x4& Q,
                                          const f32x4& V, float bb)
{
    #pragma unroll
    for (int q = 0; q < 4; ++q) {
        int row = (lane >> 4) * 4 + q;
        float pre = P[q] + Q[q] + bb;
        float h = fmaxf(pre, 0.f);
        short s0, s1, s2;
        split3f(h, s0, s1, s2);
        st_b16(t0, RS, row, col, s0);
        st_b16(t1, RS, row, col, s1);
        st_b16(t2, RS, row, col, s2);
        st_b16(tv, RS, row, col, pre > 0.f ? f2b(V[q]) : (short)0);
    }
}

// =====================================================================
template<int K>
__device__ void pack_w(const float* __restrict__ W, short* __restrict__ dst, int NK,
                       int gid, int nthr)
{
    for (int i = gid; i < NK; i += nthr) {
        int c = i / K, k = i % K;
        int cb = c >> 4, ks = k >> 5;
        int L = (((k >> 3) & 3) << 4) | (c & 15);
        int j = k & 7;
        int idx = ((cb * (K / 32) + ks) * 64 + L) * 8 + j;
        short s0, s1, s2; split3f(W[i], s0, s1, s2);
        dst[idx] = s0; dst[idx + NK] = s1; dst[idx + 2 * NK] = s2;
    }
}

__global__ void initk(const float* __restrict__ x, const float* __restrict__ xdot,
                      const float* __restrict__ We1, const float* __restrict__ We2,
                      const float* __restrict__ We3, const float* __restrict__ Wd1,
                      const float* __restrict__ Wd2, const float* __restrict__ Wd3,
                      const float* __restrict__ XI, const float* __restrict__ XIm,
                      float* __restrict__ xh, float* __restrict__ dxh,
                      short* Wp1, short* Wp2, short* Wp3, short* Wp4, short* Wp5, short* Wp6,
                      short* xiP, int2* pk)
{
    int gid = blockIdx.x * blockDim.x + threadIdx.x;
    int nthr = gridDim.x * blockDim.x;

    for (int i = gid; i < (BATCH / 16) * 16 * 64; i += nthr) {
        int L = i & 63, ks = (i >> 6) & 15, rb = i >> 10;
        int row = rb * 16 + (L & 15);
        int k0 = ks * 32 + ((L >> 4) << 3);
        const float* px = &x[(size_t)row * IN_DIM + k0];
        const float* pd = &xdot[(size_t)row * IN_DIM + k0];
        union { short s[8]; bf16x8 v; } a0, a1, a2, dv;
        #pragma unroll
        for (int j = 0; j < 8; ++j) {
            split3f(px[j], a0.s[j], a1.s[j], a2.s[j]);
            dv.s[j] = f2b(pd[j]);
        }
        short* bx = (short*)(xh + (size_t)rb * 8192);
        short* bd = (short*)(dxh + (size_t)rb * 8192);
        int off = (ks * 64 + L) * 8;
        *(bf16x8*)(bx + off) = a0.v;
        *(bf16x8*)(bx + 8192 + off) = a1.v;
        *(bf16x8*)(bd + off) = a2.v;
        *(bf16x8*)(bd + 8192 + off) = dv.v;
    }

    pack_w<512>(We1, Wp1, WSZ1, gid, nthr);
    pack_w<128>(We2, Wp2, WSZ2, gid, nthr);
    pack_w<64>(We3, Wp3, WSZ3, gid, nthr);
    pack_w<64>(Wd1, Wp4, WSZ4, gid, nthr);
    pack_w<64>(Wd2, Wp5, WSZ5, gid, nthr);
    pack_w<128>(Wd3, Wp6, WSZ6, gid, nthr);

    for (int i = gid; i < 4 * 66 * 64; i += nthr) {
        int cb = i / (66 * 64);
        int r = i - cb * (66 * 64);
        int ks = r >> 6, L = r & 63;
        int col = cb * 16 + (L & 15);
        union { short s[8]; bf16x8 v; } w;
        #pragma unroll
        for (int j = 0; j < 8; ++j) {
            int f = ks * 32 + ((L >> 4) << 3) + j;
            float v = (f < NFUNC) ? XI[(size_t)f * DDIM + col] * XIm[(size_t)f * DDIM + col] : 0.f;
            w.s[j] = f2b(v);
        }
        *(bf16x8*)(xiP + (size_t)i * 8) = w.v;
    }

    for (int f = gid; f < NFPAD; f += nthr) {
        int a, b;
        if (f == 0) { a = 64; b = 64; }
        else if (f <= DDIM) { a = f - 1; b = 64; }
        else if (f < NFUNC) {
            int p = f - 1 - DDIM; int i2 = 0, cum = 0;
            while (cum + (63 - i2) <= p) { cum += 63 - i2; ++i2; }
            a = i2; b = i2 + 1 + (p - cum);
        } else { a = 65; b = 65; }
        pk[f] = make_int2(a, b);
    }
}

// =====================================================================
// 128 blocks x 512 threads: 2 quads of 4 waves; quad q handles rows
// blockIdx*32 + q*16 with r8's per-wave code. Both quads request the same
// weight lines -> L1/L2 dedup halves global weight traffic (the r8 wall).
__global__ __launch_bounds__(512)
void fused(const float* __restrict__ be1, const float* __restrict__ be2,
           const float* __restrict__ be3, const float* __restrict__ bd1,
           const float* __restrict__ bd2, const float* __restrict__ bd3,
           const short* __restrict__ Wp1, const short* __restrict__ Wp2,
           const short* __restrict__ Wp3, const short* __restrict__ Wp4,
           const short* __restrict__ Wp5, const short* __restrict__ Wp6,
           const short* __restrict__ xiP, const int2* __restrict__ pk,
           float* __restrict__ xh, float* __restrict__ dxh, float* __restrict__ zo,
           float* __restrict__ dz, float* __restrict__ dzs)
{
    // 160 KiB shared.
    // L1 phase: per-wave DMA slots, depth 2 x 10240 B -> [0,163840) exactly.
    // After L1 barrier: per-quad alias maps at quad*37120 -> [0,74240).
    // dec3 phase: per-wave B slots depth 3 x 3072 at [74240,147968).
    __shared__ __align__(1024) char lds[163840];
#define GLL(gp, lo) __builtin_amdgcn_global_load_lds( \
        (const __attribute__((address_space(1))) unsigned int*)(gp), \
        (__attribute__((address_space(3))) unsigned int*)&lds[lo], 16, 0, 0)

    const int tid = threadIdx.x, lane = tid & 63, wave = tid >> 6;
    const int wq = wave & 3, quad = wave >> 2;
    const int qtid = tid & 255;
    const int row0 = blockIdx.x * 32 + quad * 16;
    const int c16 = lane & 15;
    const int lane16 = lane * 16;
    const int tr = qtid & 15, tf44 = (qtid >> 4) * 44;

    char* Qb = lds + quad * 37120;
    short* h1s0 = (short*)(Qb + 0);
    short* h1s1 = (short*)(Qb + 4096);
    short* h1s2 = (short*)(Qb + 8192);
    short* v1   = (short*)(Qb + 12288);
    short* h2s0 = (short*)(Qb + 16384);
    short* h2s1 = (short*)(Qb + 18432);
    short* h2s2 = (short*)(Qb + 20480);
    short* v2   = (short*)(Qb + 22528);
    short* th   = (short*)(Qb + 0);      // [16][704] swizzled
    short* g1s0 = (short*)(Qb + 0);
    short* g1s1 = (short*)(Qb + 2048);
    short* g1s2 = (short*)(Qb + 4096);
    short* u1   = (short*)(Qb + 6144);
    short* g2s0 = (short*)(Qb + 8192);
    short* g2s1 = (short*)(Qb + 12288);
    short* g2s2 = (short*)(Qb + 16384);
    short* u2   = (short*)(Qb + 20480);
    short* zb0  = (short*)(Qb + 24576);
    short* zb1  = (short*)(Qb + 26624);
    short* zb2  = (short*)(Qb + 28672);
    short* dzsb = (short*)(Qb + 30720);
    float* zf   = (float*)(Qb + 32768);  // [16][68]

    // ---- bias preload (plain loads; older vmcnt entries retire first) ----
    float bb1[2] = { be1[wq * 32 + c16], be1[wq * 32 + 16 + c16] };
    float bb2 = be2[wq * 16 + c16];
    float bb3 = be3[wq * 16 + c16];
    float bD1 = bd1[wq * 16 + c16];
    float bD2[2] = { bd2[wq * 32 + c16], bd2[wq * 32 + 16 + c16] };
    float bD3[8];
    #pragma unroll
    for (int i = 0; i < 8; ++i) bD3[i] = bd3[wq * 128 + i * 16 + c16];

    // ================= encoder L1 (K=512, N=128): DMA pipeline depth 2 ====
    f32x4 P1[2] = {}, Q1[2] = {}, V1[2] = {};
    {
        const char* bxc = (const char*)(xh + ((size_t)blockIdx.x * 2 + quad) * 8192);
        const char* bdc = (const char*)(dxh + ((size_t)blockIdx.x * 2 + quad) * 8192);
        const char* w1ac = (const char*)Wp1;
        const char* w1bc = (const char*)(Wp1 + WSZ1);
        const char* w1cc = (const char*)(Wp1 + 2 * WSZ1);
#define SLOT1(d) (unsigned)(wave * 20480 + (d) * 10240)
#define ISS1(ks, d) { unsigned sb = SLOT1(d); \
        const char* ga = bxc + (ks) * 1024 + lane16; \
        GLL(ga, sb);            GLL(ga + 16384, sb + 1024); \
        const char* gd = bdc + (ks) * 1024 + lane16; \
        GLL(gd, sb + 2048);     GLL(gd + 16384, sb + 3072); \
        int bA = ((wq * 2) * 16 + (ks)) * 1024 + lane16; \
        int bB = ((wq * 2 + 1) * 16 + (ks)) * 1024 + lane16; \
        GLL(w1ac + bA, sb + 4096); GLL(w1bc + bA, sb + 5120); GLL(w1cc + bA, sb + 6144); \
        GLL(w1ac + bB, sb + 7168); GLL(w1bc + bB, sb + 8192); GLL(w1cc + bB, sb + 9216); }
#define STEP1(ks, WN) { waitv<WN>(); unsigned sb = SLOT1((ks) & 1); \
        bf16x8 f0  = *(const bf16x8*)&lds[sb + lane16]; \
        bf16x8 f1  = *(const bf16x8*)&lds[sb + 1024 + lane16]; \
        bf16x8 f2  = *(const bf16x8*)&lds[sb + 2048 + lane16]; \
        bf16x8 fv  = *(const bf16x8*)&lds[sb + 3072 + lane16]; \
        bf16x8 b00 = *(const bf16x8*)&lds[sb + 4096 + lane16]; \
        bf16x8 b01 = *(const bf16x8*)&lds[sb + 5120 + lane16]; \
        bf16x8 b02 = *(const bf16x8*)&lds[sb + 6144 + lane16]; \
        bf16x8 b10 = *(const bf16x8*)&lds[sb + 7168 + lane16]; \
        bf16x8 b11 = *(const bf16x8*)&lds[sb + 8192 + lane16]; \
        bf16x8 b12 = *(const bf16x8*)&lds[sb + 9216 + lane16]; \
        mf9(f0, f1, f2, fv, b00, b01, b02, P1[0], Q1[0], V1[0]); \
        mf9(f0, f1, f2, fv, b10, b11, b12, P1[1], Q1[1], V1[1]); \
        __builtin_amdgcn_sched_barrier(0); \
        if ((ks) + 2 < 16) ISS1((ks) + 2, (ks) & 1) }

        ISS1(0, 0) ISS1(1, 1)
        STEP1(0, 10)  STEP1(1, 10)  STEP1(2, 10)  STEP1(3, 10)
        STEP1(4, 10)  STEP1(5, 10)  STEP1(6, 10)  STEP1(7, 10)
        STEP1(8, 10)  STEP1(9, 10)  STEP1(10, 10) STEP1(11, 10)
        STEP1(12, 10) STEP1(13, 10) STEP1(14, 10) STEP1(15, 0)
#undef ISS1
#undef STEP1
#undef SLOT1
    }
    __syncthreads();   // all waves done with pipeline slots -> alias region safe
    #pragma unroll
    for (int nf = 0; nf < 2; ++nf) {
        int col = wq * 32 + nf * 16 + c16;
        epi_store(h1s0, h1s1, h1s2, v1, 128, lane, col, P1[nf], Q1[nf], V1[nf], bb1[nf]);
    }
    // L2 B prefetch (plain loads; dup across quads -> L1 hit)
    bf16x8 L2B[4][3];
    #pragma unroll
    for (int ks = 0; ks < 4; ++ks) {
        int blk = wq * 4 + ks;
        L2B[ks][0] = ld_bp(Wp2, blk, lane);
        L2B[ks][1] = ld_bp(Wp2 + WSZ2, blk, lane);
        L2B[ks][2] = ld_bp(Wp2 + 2 * WSZ2, blk, lane);
    }
    __syncthreads();

    // ================= encoder L2 (K=128, N=64) ========
    bf16x8 L3B[2][3];
    {
        bf16x8 Aa[4][4];
        #pragma unroll
        for (int ks = 0; ks < 4; ++ks) {
            Aa[ks][0] = ld_af(h1s0, 128, lane, ks * 32);
            Aa[ks][1] = ld_af(h1s1, 128, lane, ks * 32);
            Aa[ks][2] = ld_af(h1s2, 128, lane, ks * 32);
            Aa[ks][3] = ld_af(v1, 128, lane, ks * 32);
        }
        #pragma unroll
        for (int ks = 0; ks < 2; ++ks) {
            int blk = wq * 2 + ks;
            L3B[ks][0] = ld_bp(Wp3, blk, lane);
            L3B[ks][1] = ld_bp(Wp3 + WSZ3, blk, lane);
            L3B[ks][2] = ld_bp(Wp3 + 2 * WSZ3, blk, lane);
        }
        f32x4 P = {}, Q = {}, V = {};
        #pragma unroll
        for (int ks = 0; ks < 4; ++ks)
            mf9(Aa[ks][0], Aa[ks][1], Aa[ks][2], Aa[ks][3], L2B[ks][0], L2B[ks][1], L2B[ks][2], P, Q, V);
        epi_store(h2s0, h2s1, h2s2, v2, 64, lane, wq * 16 + c16, P, Q, V, bb2);
    }
    __syncthreads();

    // ================= encoder L3 (K=64) -> z ========
    bf16x8 X[KS_PER_CHUNK];
    {
        bf16x8 Aa[2][4];
        #pragma unroll
        for (int ks = 0; ks < 2; ++ks) {
            Aa[ks][0] = ld_af(h2s0, 64, lane, ks * 32);
            Aa[ks][1] = ld_af(h2s1, 64, lane, ks * 32);
            Aa[ks][2] = ld_af(h2s2, 64, lane, ks * 32);
            Aa[ks][3] = ld_af(v2, 64, lane, ks * 32);
        }
        f32x4 P = {}, Q = {}, V = {};
        #pragma unroll
        for (int ks = 0; ks < 2; ++ks)
            mf9(Aa[ks][0], Aa[ks][1], Aa[ks][2], Aa[ks][3], L3B[ks][0], L3B[ks][1], L3B[ks][2], P, Q, V);
        #pragma unroll
        for (int kk = 0; kk < KS_PER_CHUNK; ++kk)
            X[kk] = ld_bp(xiP, wq * 66 + kk, lane);
        int col = wq * 16 + c16;
        #pragma unroll
        for (int q = 0; q < 4; ++q) {
            int row = (lane >> 4) * 4 + q;
            float pre = P[q] + Q[q] + bb3;
            float hz = fmaxf(pre, 0.f);
            float vz = pre > 0.f ? V[q] : 0.f;
            zf[row * 68 + col] = hz;
            short s0, s1, s2;
            split3f(hz, s0, s1, s2);
            st_b16(zb0, 64, row, col, s0);
            st_b16(zb1, 64, row, col, s1);
            st_b16(zb2, 64, row, col, s2);
            zo[(size_t)(row0 + row) * DDIM + col] = hz;
            dz[(size_t)(row0 + row) * DDIM + col] = vz;
        }
        if (qtid < 32) { int r = qtid & 15; zf[r * 68 + 64 + (qtid >> 4)] = (qtid >> 4) ? 0.f : 1.f; }
    }
    __syncthreads();   // zf/zb ready; h1/h2 dead -> th may overwrite

    // ================= SINDy: 3 chunks of 704 ========
    f32x4 sa0 = {}, sa1 = {};
#define BUILD(ch) { _Pragma("unroll") for (int g = 0; g < 11; ++g) { \
        int fl = tf44 + g * 4, fg = (ch) * CHUNK + fl; \
        int4 qa = *(const int4*)&pk[fg]; int4 qb = *(const int4*)&pk[fg + 2]; \
        float t0 = zf[tr * 68 + qa.x] * zf[tr * 68 + qa.y]; \
        float t1 = zf[tr * 68 + qa.z] * zf[tr * 68 + qa.w]; \
        float t2 = zf[tr * 68 + qb.x] * zf[tr * 68 + qb.y]; \
        float t3 = zf[tr * 68 + qb.z] * zf[tr * 68 + qb.w]; \
        short arr[4] = { f2b(t0), f2b(t1), f2b(t2), f2b(t3) }; \
        st_b64(th, 704, tr, fl, pk4(arr)); } }
#define SMF() { _Pragma("unroll") for (int kk = 0; kk < KS_PER_CHUNK; ++kk) { \
        bf16x8 a = ld_af(th, 704, lane, kk * 32); \
        if (kk & 1) sa1 = MFMA(a, X[kk], sa1); else sa0 = MFMA(a, X[kk], sa0); } }
#define ISX(ch) { _Pragma("unroll") for (int kk = 0; kk < KS_PER_CHUNK; ++kk) \
        X[kk] = ld_bp(xiP, wq * 66 + (ch) * KS_PER_CHUNK + kk, lane); }

    BUILD(0)
    __syncthreads();
    SMF() ISX(1)
    __syncthreads();
    BUILD(1)
    __syncthreads();
    SMF() ISX(2)
    __syncthreads();
    BUILD(2)
    __syncthreads();
    SMF()
#undef BUILD
#undef SMF
#undef ISX
    bf16x8 D1B[2][3];
    {
        f32x4 sacc = sa0 + sa1;
        #pragma unroll
        for (int ks = 0; ks < 2; ++ks) {
            int blk = wq * 2 + ks;
            D1B[ks][0] = ld_bp(Wp4, blk, lane);
            D1B[ks][1] = ld_bp(Wp4 + WSZ4, blk, lane);
            D1B[ks][2] = ld_bp(Wp4 + 2 * WSZ4, blk, lane);
        }
        int col = wq * 16 + c16;
        #pragma unroll
        for (int q = 0; q < 4; ++q) {
            int row = (lane >> 4) * 4 + q;
            float v = sacc[q];
            dzs[(size_t)(row0 + row) * DDIM + col] = v;
            st_b16(dzsb, 64, row, col, f2b(v));
        }
    }
    __syncthreads();   // dzsb ready; th dead -> g1 may overwrite

    // ================= decoder L1 (K=64) ========
    bf16x8 D2B[4][3];
    {
        bf16x8 Aa[2][4];
        #pragma unroll
        for (int ks = 0; ks < 2; ++ks) {
            Aa[ks][0] = ld_af(zb0, 64, lane, ks * 32);
            Aa[ks][1] = ld_af(zb1, 64, lane, ks * 32);
            Aa[ks][2] = ld_af(zb2, 64, lane, ks * 32);
            Aa[ks][3] = ld_af(dzsb, 64, lane, ks * 32);
        }
        #pragma unroll
        for (int cf = 0; cf < 2; ++cf)
            #pragma unroll
            for (int ks = 0; ks < 2; ++ks) {
                int blk = (wq * 2 + cf) * 2 + ks;
                D2B[cf * 2 + ks][0] = ld_bp(Wp5, blk, lane);
                D2B[cf * 2 + ks][1] = ld_bp(Wp5 + WSZ5, blk, lane);
                D2B[cf * 2 + ks][2] = ld_bp(Wp5 + 2 * WSZ5, blk, lane);
            }
        f32x4 P = {}, Q = {}, V = {};
        #pragma unroll
        for (int ks = 0; ks < 2; ++ks)
            mf9(Aa[ks][0], Aa[ks][1], Aa[ks][2], Aa[ks][3], D1B[ks][0], D1B[ks][1], D1B[ks][2], P, Q, V);
        epi_store(g1s0, g1s1, g1s2, u1, 64, lane, wq * 16 + c16, P, Q, V, bD1);
    }
    __syncthreads();

    // ================= decoder L2 (K=64, N=128) ========
    {
        bf16x8 Aa[2][4];
        #pragma unroll
        for (int ks = 0; ks < 2; ++ks) {
            Aa[ks][0] = ld_af(g1s0, 64, lane, ks * 32);
            Aa[ks][1] = ld_af(g1s1, 64, lane, ks * 32);
            Aa[ks][2] = ld_af(g1s2, 64, lane, ks * 32);
            Aa[ks][3] = ld_af(u1, 64, lane, ks * 32);
        }
        f32x4 P[2] = {}, Q[2] = {}, V[2] = {};
        #pragma unroll
        for (int cf = 0; cf < 2; ++cf)
            #pragma unroll
            for (int ks = 0; ks < 2; ++ks)
                mf9(Aa[ks][0], Aa[ks][1], Aa[ks][2], Aa[ks][3],
                    D2B[cf * 2 + ks][0], D2B[cf * 2 + ks][1], D2B[cf * 2 + ks][2],
                    P[cf], Q[cf], V[cf]);
        #pragma unroll
        for (int cf = 0; cf < 2; ++cf) {
            int col = wq * 32 + cf * 16 + c16;
            epi_store(g2s0, g2s1, g2s2, u2, 128, lane, col, P[cf], Q[cf], V[cf], bD2[cf]);
        }
    }
    __syncthreads();

    // ================= decoder L3 (K=128, N=512): DMA pipeline, depth 3 ====
    bf16x8 Ax0, Ax1, Ax2, Axv;
    const char* w6ac = (const char*)Wp6;
    const char* w6bc = (const char*)(Wp6 + WSZ6);
    const char* w6cc = (const char*)(Wp6 + 2 * WSZ6);
#define D3SLOT(d) (unsigned)(74240 + wave * 9216 + (d) * 3072)
#define D3ISS(h, s) { unsigned sb = D3SLOT((s) % 3); \
        int bo = ((wq * 8 + (h) * 4 + ((s) & 3)) * 4 + ((s) >> 2)) * 1024 + lane16; \
        GLL(w6ac + bo, sb); GLL(w6bc + bo, sb + 1024); GLL(w6cc + bo, sb + 2048); }
#define D3STEP(h, s, WN, Pa, Qa, Va) { waitv<WN>(); \
        if (((s) & 3) == 0) { int ks = (s) >> 2; \
            Ax0 = ld_af(g2s0, 128, lane, ks * 32); Ax1 = ld_af(g2s1, 128, lane, ks * 32); \
            Ax2 = ld_af(g2s2, 128, lane, ks * 32); Axv = ld_af(u2, 128, lane, ks * 32); } \
        { unsigned sb = D3SLOT((s) % 3); \
          bf16x8 c0 = *(const bf16x8*)&lds[sb + lane16]; \
          bf16x8 c1 = *(const bf16x8*)&lds[sb + 1024 + lane16]; \
          bf16x8 c2 = *(const bf16x8*)&lds[sb + 2048 + lane16]; \
          mf9(Ax0, Ax1, Ax2, Axv, c0, c1, c2, Pa[(s) & 3], Qa[(s) & 3], Va[(s) & 3]); } \
        __builtin_amdgcn_sched_barrier(0); \
        if ((s) + 3 < 16) D3ISS(h, (s) + 3) }
#define D3EPI(h, P_, Q_, V_) { _Pragma("unroll") for (int cf = 0; cf < 4; ++cf) { \
        int col = wq * 128 + (h) * 64 + cf * 16 + c16; \
        float bb = bD3[(h) * 4 + cf]; \
        _Pragma("unroll") for (int q = 0; q < 4; ++q) { \
            int row = (lane >> 4) * 4 + q; \
            float pre = P_[cf][q] + Q_[cf][q] + bb; \
            xh[(size_t)(row0 + row) * IN_DIM + col] = fmaxf(pre, 0.f); \
            dxh[(size_t)(row0 + row) * IN_DIM + col] = pre > 0.f ? V_[cf][q] : 0.f; } } }

    {
        f32x4 P[4] = {}, Q[4] = {}, V[4] = {};
        D3ISS(0, 0) D3ISS(0, 1) D3ISS(0, 2)
        D3STEP(0, 0, 6, P, Q, V)  D3STEP(0, 1, 6, P, Q, V)  D3STEP(0, 2, 6, P, Q, V)  D3STEP(0, 3, 6, P, Q, V)
        D3STEP(0, 4, 6, P, Q, V)  D3STEP(0, 5, 6, P, Q, V)  D3STEP(0, 6, 6, P, Q, V)  D3STEP(0, 7, 6, P, Q, V)
        D3STEP(0, 8, 6, P, Q, V)  D3STEP(0, 9, 6, P, Q, V)  D3STEP(0, 10, 6, P, Q, V) D3STEP(0, 11, 6, P, Q, V)
        D3STEP(0, 12, 6, P, Q, V) D3STEP(0, 13, 6, P, Q, V) D3STEP(0, 14, 3, P, Q, V) D3STEP(0, 15, 0, P, Q, V)
        D3EPI(0, P, Q, V)
    }
    {
        f32x4 P[4] = {}, Q[4] = {}, V[4] = {};
        D3ISS(1, 0) D3ISS(1, 1) D3ISS(1, 2)
        D3STEP(1, 0, 6, P, Q, V)  D3STEP(1, 1, 6, P, Q, V)  D3STEP(1, 2, 6, P, Q, V)  D3STEP(1, 3, 6, P, Q, V)
        D3STEP(1, 4, 6, P, Q, V)  D3STEP(1, 5, 6, P, Q, V)  D3STEP(1, 6, 6, P, Q, V)  D3STEP(1, 7, 6, P, Q, V)
        D3STEP(1, 8, 6, P, Q, V)  D3STEP(1, 9, 6, P, Q, V)  D3STEP(1, 10, 6, P, Q, V) D3STEP(1, 11, 6, P, Q, V)
        D3STEP(1, 12, 6, P, Q, V) D3STEP(1, 13, 6, P, Q, V) D3STEP(1, 14, 3, P, Q, V) D3STEP(1, 15, 0, P, Q, V)
        D3EPI(1, P, Q, V)
    }
#undef D3ISS
#undef D3STEP
#undef D3EPI
#undef D3SLOT
#undef GLL
}

// =====================================================================
extern "C" void kernel_launch(void* const* d_in, const int* in_sizes, int n_in,
                              void* d_out, int out_size, void* d_ws, size_t ws_size,
                              hipStream_t stream)
{
    const float* x    = (const float*)d_in[0];
    const float* xdot = (const float*)d_in[1];
    const float* We1  = (const float*)d_in[2];
    const float* be1  = (const float*)d_in[3];
    const float* We2  = (const float*)d_in[4];
    const float* be2  = (const float*)d_in[5];
    const float* We3  = (const float*)d_in[6];
    const float* be3  = (const float*)d_in[7];
    const float* Wd1  = (const float*)d_in[8];
    const float* bd1  = (const float*)d_in[9];
    const float* Wd2  = (const float*)d_in[10];
    const float* bd2  = (const float*)d_in[11];
    const float* Wd3  = (const float*)d_in[12];
    const float* bd3  = (const float*)d_in[13];
    const float* XI   = (const float*)d_in[14];
    const float* XIm  = (const float*)d_in[15];

    float* out = (float*)d_out;
    float* xh  = out;
    float* dxh = out + (size_t)BATCH * IN_DIM;
    float* zo  = dxh + (size_t)BATCH * IN_DIM;
    float* dz  = zo + (size_t)BATCH * DDIM;
    float* dzs = dz + (size_t)BATCH * DDIM;

    int2*  pk  = (int2*)d_ws;
    short* Wp1 = (short*)(pk + NFPAD);
    short* Wp2 = Wp1 + 3 * WSZ1;
    short* Wp3 = Wp2 + 3 * WSZ2;
    short* Wp4 = Wp3 + 3 * WSZ3;
    short* Wp5 = Wp4 + 3 * WSZ4;
    short* Wp6 = Wp5 + 3 * WSZ5;
    short* xiP = Wp6 + 3 * WSZ6;

    initk<<<1024, 256, 0, stream>>>(x, xdot, We1, We2, We3, Wd1, Wd2, Wd3, XI, XIm,
                                    xh, dxh, Wp1, Wp2, Wp3, Wp4, Wp5, Wp6, xiP, pk);
    fused<<<BATCH / 32, 512, 0, stream>>>(be1, be2, be3, bd1, bd2, bd3,
                                          Wp1, Wp2, Wp3, Wp4, Wp5, Wp6, xiP, pk,
                                          xh, dxh, zo, dz, dzs);
}

// Round 10
// 52.386 us; speedup vs baseline: 1.2629x; 1.2629x over previous
//
#include <hip/hip_runtime.h>

#define BATCH 4096
#define IN_DIM 512
#define H1DIM 128
#define H2DIM 64
#define DDIM 64
#define NFUNC 2081
#define NFPAD 2112
#define CHUNK 704           // 2112 = 3 * 704
#define KS_PER_CHUNK 22     // 704/32

typedef short bf16x8 __attribute__((ext_vector_type(8)));
typedef float f32x4 __attribute__((ext_vector_type(4)));
#define MFMA(a,b,c) __builtin_amdgcn_mfma_f32_16x16x32_bf16(a,b,c,0,0,0)

#define WSZ1 (H1DIM*IN_DIM)
#define WSZ2 (H2DIM*H1DIM)
#define WSZ3 (DDIM*H2DIM)
#define WSZ4 (H2DIM*DDIM)
#define WSZ5 (H1DIM*H2DIM)
#define WSZ6 (IN_DIM*H1DIM)

__device__ __forceinline__ short f2b(float f) {
    union { float f; unsigned u; } x; x.f = f;
    unsigned r = x.u + 0x7fffu + ((x.u >> 16) & 1u);
    return (short)(r >> 16);
}
__device__ __forceinline__ float b2f(short s) {
    union { unsigned u; float f; } x; x.u = ((unsigned)(unsigned short)s) << 16;
    return x.f;
}
__device__ __forceinline__ void split3f(float v, short& s0, short& s1, short& s2) {
    s0 = f2b(v); float r = v - b2f(s0);
    s1 = f2b(r); float r2 = r - b2f(s1);
    s2 = f2b(r2);
}
__device__ __forceinline__ uint2 pk4(const short* s) {
    union { short s[4]; uint2 u; } z;
    z.s[0] = s[0]; z.s[1] = s[1]; z.s[2] = s[2]; z.s[3] = s[3];
    return z.u;
}

template<int N> __device__ __forceinline__ void waitv() {
    asm volatile("s_waitcnt vmcnt(%0)" :: "n"(N) : "memory");
    __builtin_amdgcn_sched_barrier(0);
}

// ---- swizzled LDS tile helpers (row stride RS shorts, byte ^= (r&7)<<4) ----
__device__ __forceinline__ void st_b16(short* t, int RS, int r, int c, short v) {
    int b = (c * 2) ^ ((r & 7) << 4);
    *(short*)((char*)(t + r * RS) + b) = v;
}
__device__ __forceinline__ void st_b64(short* t, int RS, int r, int c0, uint2 v) {
    int b = (c0 * 2) ^ ((r & 7) << 4);
    *(uint2*)((char*)(t + r * RS) + b) = v;
}
__device__ __forceinline__ bf16x8 ld_af(const short* t, int RS, int lane, int kbase) {
    int r = lane & 15;
    int b = ((kbase + (lane >> 4) * 8) * 2) ^ ((r & 7) << 4);
    return *(const bf16x8*)((const char*)(t + r * RS) + b);
}
__device__ __forceinline__ bf16x8 ld_bp(const short* P, int blk, int lane) {
    return *(const bf16x8*)(P + ((size_t)blk * 64 + lane) * 8);
}

// 9-MFMA split-precision dual step (order identical to r8 -> same numerics)
__device__ __forceinline__ void mf9(bf16x8 f0, bf16x8 f1, bf16x8 f2, bf16x8 fv,
                                    bf16x8 b0, bf16x8 b1, bf16x8 b2,
                                    f32x4& P, f32x4& Q, f32x4& V) {
    P = MFMA(f0, b0, P); Q = MFMA(f1, b1, Q);
    P = MFMA(f1, b0, P); Q = MFMA(f0, b1, Q);
    P = MFMA(f2, b0, P); Q = MFMA(f2, b1, Q);
    P = MFMA(f0, b2, P); Q = MFMA(f1, b2, Q);
    V = MFMA(fv, b0, V);
}

__device__ __forceinline__ void epi_store(short* t0, short* t1, short* t2, short* tv, int RS,
                                          int lane, int col, const f32x4& P, const f32x4& Q,
                                          const f32x4& V, float bb)
{
    #pragma unroll
    for (int q = 0; q < 4; ++q) {
        int row = (lane >> 4) * 4 + q;
        float pre = P[q] + Q[q] + bb;
        float h = fmaxf(pre, 0.f);
        short s0, s1, s2;
        split3f(h, s0, s1, s2);
        st_b16(t0, RS, row, col, s0);
        st_b16(t1, RS, row, col, s1);
        st_b16(t2, RS, row, col, s2);
        st_b16(tv, RS, row, col, pre > 0.f ? f2b(V[q]) : (short)0);
    }
}

// =====================================================================
template<int K>
__device__ void pack_w(const float* __restrict__ W, short* __restrict__ dst, int NK,
                       int gid, int nthr)
{
    // octet version: 16B vector stores, contiguous 8-k reads
    for (int o = gid; o < NK / 8; o += nthr) {
        int c = o / (K / 8), k0 = (o - c * (K / 8)) * 8;
        int cb = c >> 4, ks = k0 >> 5;
        int L = (((k0 >> 3) & 3) << 4) | (c & 15);
        int idx = ((cb * (K / 32) + ks) * 64 + L) * 8;
        union { short s[8]; bf16x8 v; } p0, p1, p2;
        #pragma unroll
        for (int j = 0; j < 8; ++j)
            split3f(W[(size_t)c * K + k0 + j], p0.s[j], p1.s[j], p2.s[j]);
        *(bf16x8*)(dst + idx) = p0.v;
        *(bf16x8*)(dst + NK + idx) = p1.v;
        *(bf16x8*)(dst + 2 * NK + idx) = p2.v;
    }
}

__global__ void initk(const float* __restrict__ x, const float* __restrict__ xdot,
                      const float* __restrict__ We1, const float* __restrict__ We2,
                      const float* __restrict__ We3, const float* __restrict__ Wd1,
                      const float* __restrict__ Wd2, const float* __restrict__ Wd3,
                      const float* __restrict__ XI, const float* __restrict__ XIm,
                      float* __restrict__ xh, float* __restrict__ dxh,
                      short* Wp1, short* Wp2, short* Wp3, short* Wp4, short* Wp5, short* Wp6,
                      short* xiP, int2* pk)
{
    int gid = blockIdx.x * blockDim.x + threadIdx.x;
    int nthr = gridDim.x * blockDim.x;

    for (int i = gid; i < (BATCH / 16) * 16 * 64; i += nthr) {
        int L = i & 63, ks = (i >> 6) & 15, rb = i >> 10;
        int row = rb * 16 + (L & 15);
        int k0 = ks * 32 + ((L >> 4) << 3);
        const float* px = &x[(size_t)row * IN_DIM + k0];
        const float* pd = &xdot[(size_t)row * IN_DIM + k0];
        f32x4 xa = *(const f32x4*)px, xb = *(const f32x4*)(px + 4);
        f32x4 da = *(const f32x4*)pd, db = *(const f32x4*)(pd + 4);
        union { short s[8]; bf16x8 v; } a0, a1, a2, dv;
        #pragma unroll
        for (int j = 0; j < 4; ++j) {
            split3f(xa[j], a0.s[j], a1.s[j], a2.s[j]);
            split3f(xb[j], a0.s[j + 4], a1.s[j + 4], a2.s[j + 4]);
            dv.s[j] = f2b(da[j]); dv.s[j + 4] = f2b(db[j]);
        }
        short* bx = (short*)(xh + (size_t)rb * 8192);
        short* bd = (short*)(dxh + (size_t)rb * 8192);
        int off = (ks * 64 + L) * 8;
        *(bf16x8*)(bx + off) = a0.v;
        *(bf16x8*)(bx + 8192 + off) = a1.v;
        *(bf16x8*)(bd + off) = a2.v;
        *(bf16x8*)(bd + 8192 + off) = dv.v;
    }

    pack_w<512>(We1, Wp1, WSZ1, gid, nthr);
    pack_w<128>(We2, Wp2, WSZ2, gid, nthr);
    pack_w<64>(We3, Wp3, WSZ3, gid, nthr);
    pack_w<64>(Wd1, Wp4, WSZ4, gid, nthr);
    pack_w<64>(Wd2, Wp5, WSZ5, gid, nthr);
    pack_w<128>(Wd3, Wp6, WSZ6, gid, nthr);

    for (int i = gid; i < 4 * 66 * 64; i += nthr) {
        int cb = i / (66 * 64);
        int r = i - cb * (66 * 64);
        int ks = r >> 6, L = r & 63;
        int col = cb * 16 + (L & 15);
        union { short s[8]; bf16x8 v; } w;
        #pragma unroll
        for (int j = 0; j < 8; ++j) {
            int f = ks * 32 + ((L >> 4) << 3) + j;
            float v = (f < NFUNC) ? XI[(size_t)f * DDIM + col] * XIm[(size_t)f * DDIM + col] : 0.f;
            w.s[j] = f2b(v);
        }
        *(bf16x8*)(xiP + (size_t)i * 8) = w.v;
    }

    for (int f = gid; f < NFPAD; f += nthr) {
        int a, b;
        if (f == 0) { a = 64; b = 64; }
        else if (f <= DDIM) { a = f - 1; b = 64; }
        else if (f < NFUNC) {
            int p = f - 1 - DDIM; int i2 = 0, cum = 0;
            while (cum + (63 - i2) <= p) { cum += 63 - i2; ++i2; }
            a = i2; b = i2 + 1 + (p - cum);
        } else { a = 65; b = 65; }
        pk[f] = make_int2(a, b);
    }
}

// =====================================================================
// 256 blocks x 256 threads, LDS exactly 80 KiB -> 2 blocks/CU.
// Pipelines are ROLLED loops (small I-footprint), DMA via global_load_lds
// with counted vmcnt; numerics identical to r8.
__global__ __launch_bounds__(256, 2)
void fused(const float* __restrict__ be1, const float* __restrict__ be2,
           const float* __restrict__ be3, const float* __restrict__ bd1,
           const float* __restrict__ bd2, const float* __restrict__ bd3,
           const short* __restrict__ Wp1, const short* __restrict__ Wp2,
           const short* __restrict__ Wp3, const short* __restrict__ Wp4,
           const short* __restrict__ Wp5, const short* __restrict__ Wp6,
           const short* __restrict__ xiP, const int2* __restrict__ pk,
           float* __restrict__ xh, float* __restrict__ dxh, float* __restrict__ zo,
           float* __restrict__ dz, float* __restrict__ dzs)
{
    // L1 phase: per-wave depth-2 slots, 4 waves x 2 x 10240 = [0,81920).
    // After L1 barrier: alias map [0,37120).
    // dec3 phase: per-wave depth-4 B slots at [24576,73728) (zb/dzsb/zf dead).
    __shared__ __align__(1024) char lds[81920];
#define GLL(gp, lo) __builtin_amdgcn_global_load_lds( \
        (const __attribute__((address_space(1))) unsigned int*)(gp), \
        (__attribute__((address_space(3))) unsigned int*)&lds[lo], 16, 0, 0)

    short* h1s0 = (short*)(lds + 0);
    short* h1s1 = (short*)(lds + 4096);
    short* h1s2 = (short*)(lds + 8192);
    short* v1   = (short*)(lds + 12288);
    short* h2s0 = (short*)(lds + 16384);
    short* h2s1 = (short*)(lds + 18432);
    short* h2s2 = (short*)(lds + 20480);
    short* v2   = (short*)(lds + 22528);
    short* th   = (short*)(lds + 0);      // [16][704] swizzled
    short* g1s0 = (short*)(lds + 0);
    short* g1s1 = (short*)(lds + 2048);
    short* g1s2 = (short*)(lds + 4096);
    short* u1   = (short*)(lds + 6144);
    short* g2s0 = (short*)(lds + 8192);
    short* g2s1 = (short*)(lds + 12288);
    short* g2s2 = (short*)(lds + 16384);
    short* u2   = (short*)(lds + 20480);
    short* zb0  = (short*)(lds + 24576);
    short* zb1  = (short*)(lds + 26624);
    short* zb2  = (short*)(lds + 28672);
    short* dzsb = (short*)(lds + 30720);
    float* zf   = (float*)(lds + 32768);  // [16][68]

    const int tid = threadIdx.x, lane = tid & 63, wave = tid >> 6;
    const int row0 = blockIdx.x * 16;
    const int c16 = lane & 15;
    const int lane16 = lane * 16;
    const int tr = tid & 15, tf44 = (tid >> 4) * 44;

    const char* bxc = (const char*)(xh + (size_t)blockIdx.x * 8192);
    const char* bdc = (const char*)(dxh + (size_t)blockIdx.x * 8192);
    const char* w1ac = (const char*)Wp1;
    const char* w1bc = (const char*)(Wp1 + WSZ1);
    const char* w1cc = (const char*)(Wp1 + 2 * WSZ1);

    // ---- bias preload (older vmcnt entries retire before any counted wait) ----
    float bb1[2] = { be1[wave * 32 + c16], be1[wave * 32 + 16 + c16] };
    float bb2 = be2[wave * 16 + c16];
    float bb3 = be3[wave * 16 + c16];
    float bD1 = bd1[wave * 16 + c16];
    float bD2[2] = { bd2[wave * 32 + c16], bd2[wave * 32 + 16 + c16] };

    // ================= encoder L1 (K=512, N=128): rolled DMA pipeline, depth 2 ====
    f32x4 P1[2] = {}, Q1[2] = {}, V1[2] = {};
    {
        const unsigned slotb = wave * 20480;
        auto iss1 = [&](int ks, int d) {
            unsigned sb = slotb + d * 10240;
            const char* ga = bxc + ks * 1024 + lane16;
            GLL(ga, sb);            GLL(ga + 16384, sb + 1024);
            const char* gd = bdc + ks * 1024 + lane16;
            GLL(gd, sb + 2048);     GLL(gd + 16384, sb + 3072);
            int bA = ((wave * 2) * 16 + ks) * 1024 + lane16;
            int bB = ((wave * 2 + 1) * 16 + ks) * 1024 + lane16;
            GLL(w1ac + bA, sb + 4096); GLL(w1bc + bA, sb + 5120); GLL(w1cc + bA, sb + 6144);
            GLL(w1ac + bB, sb + 7168); GLL(w1bc + bB, sb + 8192); GLL(w1cc + bB, sb + 9216);
        };
        auto step1 = [&](int ks) {
            unsigned sb = slotb + (ks & 1) * 10240;
            bf16x8 f0  = *(const bf16x8*)&lds[sb + lane16];
            bf16x8 f1  = *(const bf16x8*)&lds[sb + 1024 + lane16];
            bf16x8 f2  = *(const bf16x8*)&lds[sb + 2048 + lane16];
            bf16x8 fv  = *(const bf16x8*)&lds[sb + 3072 + lane16];
            bf16x8 b00 = *(const bf16x8*)&lds[sb + 4096 + lane16];
            bf16x8 b01 = *(const bf16x8*)&lds[sb + 5120 + lane16];
            bf16x8 b02 = *(const bf16x8*)&lds[sb + 6144 + lane16];
            bf16x8 b10 = *(const bf16x8*)&lds[sb + 7168 + lane16];
            bf16x8 b11 = *(const bf16x8*)&lds[sb + 8192 + lane16];
            bf16x8 b12 = *(const bf16x8*)&lds[sb + 9216 + lane16];
            mf9(f0, f1, f2, fv, b00, b01, b02, P1[0], Q1[0], V1[0]);
            mf9(f0, f1, f2, fv, b10, b11, b12, P1[1], Q1[1], V1[1]);
            __builtin_amdgcn_sched_barrier(0);
        };
        iss1(0, 0); iss1(1, 1);
        #pragma clang loop unroll(disable)
        for (int ks = 0; ks < 14; ++ks) {
            waitv<10>();
            step1(ks);
            iss1(ks + 2, ks & 1);
        }
        waitv<10>(); step1(14);
        waitv<0>();  step1(15);
    }
    __syncthreads();   // all waves done with slots -> alias region safe
    #pragma unroll
    for (int nf = 0; nf < 2; ++nf) {
        int col = wave * 32 + nf * 16 + c16;
        epi_store(h1s0, h1s1, h1s2, v1, 128, lane, col, P1[nf], Q1[nf], V1[nf], bb1[nf]);
    }
    bf16x8 L2B[4][3];
    #pragma unroll
    for (int ks = 0; ks < 4; ++ks) {
        int blk = wave * 4 + ks;
        L2B[ks][0] = ld_bp(Wp2, blk, lane);
        L2B[ks][1] = ld_bp(Wp2 + WSZ2, blk, lane);
        L2B[ks][2] = ld_bp(Wp2 + 2 * WSZ2, blk, lane);
    }
    __syncthreads();

    // ================= encoder L2 (K=128, N=64) ========
    bf16x8 L3B[2][3];
    {
        bf16x8 Aa[4][4];
        #pragma unroll
        for (int ks = 0; ks < 4; ++ks) {
            Aa[ks][0] = ld_af(h1s0, 128, lane, ks * 32);
            Aa[ks][1] = ld_af(h1s1, 128, lane, ks * 32);
            Aa[ks][2] = ld_af(h1s2, 128, lane, ks * 32);
            Aa[ks][3] = ld_af(v1, 128, lane, ks * 32);
        }
        #pragma unroll
        for (int ks = 0; ks < 2; ++ks) {
            int blk = wave * 2 + ks;
            L3B[ks][0] = ld_bp(Wp3, blk, lane);
            L3B[ks][1] = ld_bp(Wp3 + WSZ3, blk, lane);
            L3B[ks][2] = ld_bp(Wp3 + 2 * WSZ3, blk, lane);
        }
        f32x4 P = {}, Q = {}, V = {};
        #pragma unroll
        for (int ks = 0; ks < 4; ++ks)
            mf9(Aa[ks][0], Aa[ks][1], Aa[ks][2], Aa[ks][3], L2B[ks][0], L2B[ks][1], L2B[ks][2], P, Q, V);
        epi_store(h2s0, h2s1, h2s2, v2, 64, lane, wave * 16 + c16, P, Q, V, bb2);
    }
    __syncthreads();

    // ================= encoder L3 (K=64) -> z ========
    bf16x8 X[KS_PER_CHUNK];
    {
        bf16x8 Aa[2][4];
        #pragma unroll
        for (int ks = 0; ks < 2; ++ks) {
            Aa[ks][0] = ld_af(h2s0, 64, lane, ks * 32);
            Aa[ks][1] = ld_af(h2s1, 64, lane, ks * 32);
            Aa[ks][2] = ld_af(h2s2, 64, lane, ks * 32);
            Aa[ks][3] = ld_af(v2, 64, lane, ks * 32);
        }
        f32x4 P = {}, Q = {}, V = {};
        #pragma unroll
        for (int ks = 0; ks < 2; ++ks)
            mf9(Aa[ks][0], Aa[ks][1], Aa[ks][2], Aa[ks][3], L3B[ks][0], L3B[ks][1], L3B[ks][2], P, Q, V);
        #pragma unroll
        for (int kk = 0; kk < KS_PER_CHUNK; ++kk)
            X[kk] = ld_bp(xiP, wave * 66 + kk, lane);
        int col = wave * 16 + c16;
        #pragma unroll
        for (int q = 0; q < 4; ++q) {
            int row = (lane >> 4) * 4 + q;
            float pre = P[q] + Q[q] + bb3;
            float hz = fmaxf(pre, 0.f);
            float vz = pre > 0.f ? V[q] : 0.f;
            zf[row * 68 + col] = hz;
            short s0, s1, s2;
            split3f(hz, s0, s1, s2);
            st_b16(zb0, 64, row, col, s0);
            st_b16(zb1, 64, row, col, s1);
            st_b16(zb2, 64, row, col, s2);
            zo[(size_t)(row0 + row) * DDIM + col] = hz;
            dz[(size_t)(row0 + row) * DDIM + col] = vz;
        }
        if (tid < 32) { int r = tid & 15; zf[r * 68 + 64 + (tid >> 4)] = (tid >> 4) ? 0.f : 1.f; }
    }
    __syncthreads();   // zf/zb ready; h1/h2 dead -> th may overwrite

    // ================= SINDy: 3 chunks of 704 (BUILD rolled) ========
    f32x4 sa0 = {}, sa1 = {};
    auto build = [&](int ch) {
        #pragma clang loop unroll(disable)
        for (int g = 0; g < 11; ++g) {
            int fl = tf44 + g * 4, fg = ch * CHUNK + fl;
            int4 qa = *(const int4*)&pk[fg];
            int4 qb = *(const int4*)&pk[fg + 2];
            float t0 = zf[tr * 68 + qa.x] * zf[tr * 68 + qa.y];
            float t1 = zf[tr * 68 + qa.z] * zf[tr * 68 + qa.w];
            float t2 = zf[tr * 68 + qb.x] * zf[tr * 68 + qb.y];
            float t3 = zf[tr * 68 + qb.z] * zf[tr * 68 + qb.w];
            short arr[4] = { f2b(t0), f2b(t1), f2b(t2), f2b(t3) };
            st_b64(th, 704, tr, fl, pk4(arr));
        }
    };
#define SMF() { _Pragma("unroll") for (int kk = 0; kk < KS_PER_CHUNK; ++kk) { \
        bf16x8 a = ld_af(th, 704, lane, kk * 32); \
        if (kk & 1) sa1 = MFMA(a, X[kk], sa1); else sa0 = MFMA(a, X[kk], sa0); } }
#define ISX(ch) { _Pragma("unroll") for (int kk = 0; kk < KS_PER_CHUNK; ++kk) \
        X[kk] = ld_bp(xiP, wave * 66 + (ch) * KS_PER_CHUNK + kk, lane); }

    build(0);
    __syncthreads();
    SMF() ISX(1)
    __syncthreads();
    build(1);
    __syncthreads();
    SMF() ISX(2)
    __syncthreads();
    build(2);
    __syncthreads();
    SMF()
#undef SMF
#undef ISX
    bf16x8 D1B[2][3];
    {
        f32x4 sacc = sa0 + sa1;
        #pragma unroll
        for (int ks = 0; ks < 2; ++ks) {
            int blk = wave * 2 + ks;
            D1B[ks][0] = ld_bp(Wp4, blk, lane);
            D1B[ks][1] = ld_bp(Wp4 + WSZ4, blk, lane);
            D1B[ks][2] = ld_bp(Wp4 + 2 * WSZ4, blk, lane);
        }
        int col = wave * 16 + c16;
        #pragma unroll
        for (int q = 0; q < 4; ++q) {
            int row = (lane >> 4) * 4 + q;
            float v = sacc[q];
            dzs[(size_t)(row0 + row) * DDIM + col] = v;
            st_b16(dzsb, 64, row, col, f2b(v));
        }
    }
    __syncthreads();   // dzsb ready; th dead -> g1 may overwrite

    // ================= decoder L1 (K=64) ========
    bf16x8 D2B[4][3];
    {
        bf16x8 Aa[2][4];
        #pragma unroll
        for (int ks = 0; ks < 2; ++ks) {
            Aa[ks][0] = ld_af(zb0, 64, lane, ks * 32);
            Aa[ks][1] = ld_af(zb1, 64, lane, ks * 32);
            Aa[ks][2] = ld_af(zb2, 64, lane, ks * 32);
            Aa[ks][3] = ld_af(dzsb, 64, lane, ks * 32);
        }
        #pragma unroll
        for (int cf = 0; cf < 2; ++cf)
            #pragma unroll
            for (int ks = 0; ks < 2; ++ks) {
                int blk = (wave * 2 + cf) * 2 + ks;
                D2B[cf * 2 + ks][0] = ld_bp(Wp5, blk, lane);
                D2B[cf * 2 + ks][1] = ld_bp(Wp5 + WSZ5, blk, lane);
                D2B[cf * 2 + ks][2] = ld_bp(Wp5 + 2 * WSZ5, blk, lane);
            }
        f32x4 P = {}, Q = {}, V = {};
        #pragma unroll
        for (int ks = 0; ks < 2; ++ks)
            mf9(Aa[ks][0], Aa[ks][1], Aa[ks][2], Aa[ks][3], D1B[ks][0], D1B[ks][1], D1B[ks][2], P, Q, V);
        epi_store(g1s0, g1s1, g1s2, u1, 64, lane, wave * 16 + c16, P, Q, V, bD1);
    }
    __syncthreads();

    // ================= decoder L2 (K=64, N=128) ========
    {
        bf16x8 Aa[2][4];
        #pragma unroll
        for (int ks = 0; ks < 2; ++ks) {
            Aa[ks][0] = ld_af(g1s0, 64, lane, ks * 32);
            Aa[ks][1] = ld_af(g1s1, 64, lane, ks * 32);
            Aa[ks][2] = ld_af(g1s2, 64, lane, ks * 32);
            Aa[ks][3] = ld_af(u1, 64, lane, ks * 32);
        }
        f32x4 P[2] = {}, Q[2] = {}, V[2] = {};
        #pragma unroll
        for (int cf = 0; cf < 2; ++cf)
            #pragma unroll
            for (int ks = 0; ks < 2; ++ks)
                mf9(Aa[ks][0], Aa[ks][1], Aa[ks][2], Aa[ks][3],
                    D2B[cf * 2 + ks][0], D2B[cf * 2 + ks][1], D2B[cf * 2 + ks][2],
                    P[cf], Q[cf], V[cf]);
        #pragma unroll
        for (int cf = 0; cf < 2; ++cf) {
            int col = wave * 32 + cf * 16 + c16;
            epi_store(g2s0, g2s1, g2s2, u2, 128, lane, col, P[cf], Q[cf], V[cf], bD2[cf]);
        }
    }
    __syncthreads();

    // ================= decoder L3 (K=128, N=512): rolled DMA pipeline, depth 4 ====
    {
        const char* w6ac = (const char*)Wp6;
        const char* w6bc = (const char*)(Wp6 + WSZ6);
        const char* w6cc = (const char*)(Wp6 + 2 * WSZ6);
        const unsigned d3b = 24576 + wave * 12288;
        #pragma clang loop unroll(disable)
        for (int h = 0; h < 2; ++h) {
            auto d3iss = [&](int s) {   // slot = s&3
                unsigned sb = d3b + (s & 3) * 3072;
                int bo = ((wave * 8 + h * 4 + (s & 3)) * 4 + (s >> 2)) * 1024 + lane16;
                GLL(w6ac + bo, sb); GLL(w6bc + bo, sb + 1024); GLL(w6cc + bo, sb + 2048);
            };
            f32x4 P[4] = {}, Q[4] = {}, V[4] = {};
            d3iss(0); d3iss(1); d3iss(2); d3iss(3);
            bf16x8 Ax0, Ax1, Ax2, Axv;
#define D3C(cf) { unsigned sb = d3b + (cf) * 3072; \
            bf16x8 c0 = *(const bf16x8*)&lds[sb + lane16]; \
            bf16x8 c1 = *(const bf16x8*)&lds[sb + 1024 + lane16]; \
            bf16x8 c2 = *(const bf16x8*)&lds[sb + 2048 + lane16]; \
            mf9(Ax0, Ax1, Ax2, Axv, c0, c1, c2, P[cf], Q[cf], V[cf]); \
            __builtin_amdgcn_sched_barrier(0); }
            #pragma clang loop unroll(disable)
            for (int ks = 0; ks < 3; ++ks) {
                Ax0 = ld_af(g2s0, 128, lane, ks * 32); Ax1 = ld_af(g2s1, 128, lane, ks * 32);
                Ax2 = ld_af(g2s2, 128, lane, ks * 32); Axv = ld_af(u2, 128, lane, ks * 32);
                waitv<9>(); D3C(0) d3iss(ks * 4 + 4);
                waitv<9>(); D3C(1) d3iss(ks * 4 + 5);
                waitv<9>(); D3C(2) d3iss(ks * 4 + 6);
                waitv<9>(); D3C(3) d3iss(ks * 4 + 7);
            }
            Ax0 = ld_af(g2s0, 128, lane, 96); Ax1 = ld_af(g2s1, 128, lane, 96);
            Ax2 = ld_af(g2s2, 128, lane, 96); Axv = ld_af(u2, 128, lane, 96);
            waitv<9>(); D3C(0)
            waitv<6>(); D3C(1)
            waitv<3>(); D3C(2)
            waitv<0>(); D3C(3)
#undef D3C
            #pragma unroll
            for (int cf = 0; cf < 4; ++cf) {
                int col = wave * 128 + h * 64 + cf * 16 + c16;
                float bb = bd3[col];
                #pragma unroll
                for (int q = 0; q < 4; ++q) {
                    int row = (lane >> 4) * 4 + q;
                    float pre = P[cf][q] + Q[cf][q] + bb;
                    xh[(size_t)(row0 + row) * IN_DIM + col] = fmaxf(pre, 0.f);
                    dxh[(size_t)(row0 + row) * IN_DIM + col] = pre > 0.f ? V[cf][q] : 0.f;
                }
            }
        }
    }
#undef GLL
}

// =====================================================================
extern "C" void kernel_launch(void* const* d_in, const int* in_sizes, int n_in,
                              void* d_out, int out_size, void* d_ws, size_t ws_size,
                              hipStream_t stream)
{
    const float* x    = (const float*)d_in[0];
    const float* xdot = (const float*)d_in[1];
    const float* We1  = (const float*)d_in[2];
    const float* be1  = (const float*)d_in[3];
    const float* We2  = (const float*)d_in[4];
    const float* be2  = (const float*)d_in[5];
    const float* We3  = (const float*)d_in[6];
    const float* be3  = (const float*)d_in[7];
    const float* Wd1  = (const float*)d_in[8];
    const float* bd1  = (const float*)d_in[9];
    const float* Wd2  = (const float*)d_in[10];
    const float* bd2  = (const float*)d_in[11];
    const float* Wd3  = (const float*)d_in[12];
    const float* bd3  = (const float*)d_in[13];
    const float* XI   = (const float*)d_in[14];
    const float* XIm  = (const float*)d_in[15];

    float* out = (float*)d_out;
    float* xh  = out;
    float* dxh = out + (size_t)BATCH * IN_DIM;
    float* zo  = dxh + (size_t)BATCH * IN_DIM;
    float* dz  = zo + (size_t)BATCH * DDIM;
    float* dzs = dz + (size_t)BATCH * DDIM;

    int2*  pk  = (int2*)d_ws;
    short* Wp1 = (short*)(pk + NFPAD);
    short* Wp2 = Wp1 + 3 * WSZ1;
    short* Wp3 = Wp2 + 3 * WSZ2;
    short* Wp4 = Wp3 + 3 * WSZ3;
    short* Wp5 = Wp4 + 3 * WSZ4;
    short* Wp6 = Wp5 + 3 * WSZ5;
    short* xiP = Wp6 + 3 * WSZ6;

    initk<<<1024, 256, 0, stream>>>(x, xdot, We1, We2, We3, Wd1, Wd2, Wd3, XI, XIm,
                                    xh, dxh, Wp1, Wp2, Wp3, Wp4, Wp5, Wp6, xiP, pk);
    fused<<<BATCH / 16, 256, 0, stream>>>(be1, be2, be3, bd1, bd2, bd3,
                                          Wp1, Wp2, Wp3, Wp4, Wp5, Wp6, xiP, pk,
                                          xh, dxh, zo, dz, dzs);
}

// Round 11
// 50.187 us; speedup vs baseline: 1.3182x; 1.0438x over previous
//
#include <hip/hip_runtime.h>

#define BATCH 4096
#define IN_DIM 512
#define H1DIM 128
#define H2DIM 64
#define DDIM 64
#define NFUNC 2081
#define NFPAD 2112
#define CHUNK 704           // 2112 = 3 * 704
#define KS_PER_CHUNK 22     // 704/32

typedef short bf16x8 __attribute__((ext_vector_type(8)));
typedef float f32x4 __attribute__((ext_vector_type(4)));
#define MFMA(a,b,c) __builtin_amdgcn_mfma_f32_16x16x32_bf16(a,b,c,0,0,0)

#define WSZ1 (H1DIM*IN_DIM)
#define WSZ2 (H2DIM*H1DIM)
#define WSZ3 (DDIM*H2DIM)
#define WSZ4 (H2DIM*DDIM)
#define WSZ5 (H1DIM*H2DIM)
#define WSZ6 (IN_DIM*H1DIM)

__device__ __forceinline__ short f2b(float f) {
    union { float f; unsigned u; } x; x.f = f;
    unsigned r = x.u + 0x7fffu + ((x.u >> 16) & 1u);
    return (short)(r >> 16);
}
__device__ __forceinline__ float b2f(short s) {
    union { unsigned u; float f; } x; x.u = ((unsigned)(unsigned short)s) << 16;
    return x.f;
}
__device__ __forceinline__ void split3f(float v, short& s0, short& s1, short& s2) {
    s0 = f2b(v); float r = v - b2f(s0);
    s1 = f2b(r); float r2 = r - b2f(s1);
    s2 = f2b(r2);
}

// ---- swizzled LDS tile helpers (row stride RS shorts, byte ^= (r&7)<<4) ----
__device__ __forceinline__ void st_b16(short* t, int RS, int r, int c, short v) {
    int b = (c * 2) ^ ((r & 7) << 4);
    *(short*)((char*)(t + r * RS) + b) = v;
}
__device__ __forceinline__ void st_b32s(short* t, int RS, int r, int c, unsigned v) {
    int b = (c * 2) ^ ((r & 7) << 4);   // c even -> 4B aligned
    *(unsigned*)((char*)(t + r * RS) + b) = v;
}
__device__ __forceinline__ bf16x8 ld_af(const short* t, int RS, int lane, int kbase) {
    int r = lane & 15;
    int b = ((kbase + (lane >> 4) * 8) * 2) ^ ((r & 7) << 4);
    return *(const bf16x8*)((const char*)(t + r * RS) + b);
}
__device__ __forceinline__ bf16x8 ld_bp(const short* P, int blk, int lane) {
    return *(const bf16x8*)(P + ((size_t)blk * 64 + lane) * 8);
}

// 9-MFMA split-precision dual step (order identical to r5/r10 -> same numerics)
__device__ __forceinline__ void mf9(bf16x8 f0, bf16x8 f1, bf16x8 f2, bf16x8 fv,
                                    bf16x8 b0, bf16x8 b1, bf16x8 b2,
                                    f32x4& P, f32x4& Q, f32x4& V) {
    P = MFMA(f0, b0, P); Q = MFMA(f1, b1, Q);
    P = MFMA(f1, b0, P); Q = MFMA(f0, b1, Q);
    P = MFMA(f2, b0, P); Q = MFMA(f2, b1, Q);
    P = MFMA(f0, b2, P); Q = MFMA(f1, b2, Q);
    V = MFMA(fv, b0, V);
}

__device__ __forceinline__ void epi_store(short* t0, short* t1, short* t2, short* tv, int RS,
                                          int lane, int col, const f32x4& P, const f32x4& Q,
                                          const f32x4& V, float bb)
{
    #pragma unroll
    for (int q = 0; q < 4; ++q) {
        int row = (lane >> 4) * 4 + q;
        float pre = P[q] + Q[q] + bb;
        float h = fmaxf(pre, 0.f);
        short s0, s1, s2;
        split3f(h, s0, s1, s2);
        st_b16(t0, RS, row, col, s0);
        st_b16(t1, RS, row, col, s1);
        st_b16(t2, RS, row, col, s2);
        st_b16(tv, RS, row, col, pre > 0.f ? f2b(V[q]) : (short)0);
    }
}

// =====================================================================
template<int K>
__device__ void pack_w(const float* __restrict__ W, short* __restrict__ dst, int NK,
                       int gid, int nthr)
{
    for (int o = gid; o < NK / 8; o += nthr) {
        int c = o / (K / 8), k0 = (o - c * (K / 8)) * 8;
        int cb = c >> 4, ks = k0 >> 5;
        int L = (((k0 >> 3) & 3) << 4) | (c & 15);
        int idx = ((cb * (K / 32) + ks) * 64 + L) * 8;
        union { short s[8]; bf16x8 v; } p0, p1, p2;
        #pragma unroll
        for (int j = 0; j < 8; ++j)
            split3f(W[(size_t)c * K + k0 + j], p0.s[j], p1.s[j], p2.s[j]);
        *(bf16x8*)(dst + idx) = p0.v;
        *(bf16x8*)(dst + NK + idx) = p1.v;
        *(bf16x8*)(dst + 2 * NK + idx) = p2.v;
    }
}

__global__ void initk(const float* __restrict__ x, const float* __restrict__ xdot,
                      const float* __restrict__ We1, const float* __restrict__ We2,
                      const float* __restrict__ We3, const float* __restrict__ Wd1,
                      const float* __restrict__ Wd2, const float* __restrict__ Wd3,
                      const float* __restrict__ XI, const float* __restrict__ XIm,
                      float* __restrict__ xh, float* __restrict__ dxh,
                      short* Wp1, short* Wp2, short* Wp3, short* Wp4, short* Wp5, short* Wp6,
                      short* xiP, int2* pk)
{
    int gid = blockIdx.x * blockDim.x + threadIdx.x;
    int nthr = gridDim.x * blockDim.x;

    for (int i = gid; i < (BATCH / 16) * 16 * 64; i += nthr) {
        int L = i & 63, ks = (i >> 6) & 15, rb = i >> 10;
        int row = rb * 16 + (L & 15);
        int k0 = ks * 32 + ((L >> 4) << 3);
        const float* px = &x[(size_t)row * IN_DIM + k0];
        const float* pd = &xdot[(size_t)row * IN_DIM + k0];
        f32x4 xa = *(const f32x4*)px, xb = *(const f32x4*)(px + 4);
        f32x4 da = *(const f32x4*)pd, db = *(const f32x4*)(pd + 4);
        union { short s[8]; bf16x8 v; } a0, a1, a2, dv;
        #pragma unroll
        for (int j = 0; j < 4; ++j) {
            split3f(xa[j], a0.s[j], a1.s[j], a2.s[j]);
            split3f(xb[j], a0.s[j + 4], a1.s[j + 4], a2.s[j + 4]);
            dv.s[j] = f2b(da[j]); dv.s[j + 4] = f2b(db[j]);
        }
        short* bx = (short*)(xh + (size_t)rb * 8192);
        short* bd = (short*)(dxh + (size_t)rb * 8192);
        int off = (ks * 64 + L) * 8;
        *(bf16x8*)(bx + off) = a0.v;
        *(bf16x8*)(bx + 8192 + off) = a1.v;
        *(bf16x8*)(bd + off) = a2.v;
        *(bf16x8*)(bd + 8192 + off) = dv.v;
    }

    pack_w<512>(We1, Wp1, WSZ1, gid, nthr);
    pack_w<128>(We2, Wp2, WSZ2, gid, nthr);
    pack_w<64>(We3, Wp3, WSZ3, gid, nthr);
    pack_w<64>(Wd1, Wp4, WSZ4, gid, nthr);
    pack_w<64>(Wd2, Wp5, WSZ5, gid, nthr);
    pack_w<128>(Wd3, Wp6, WSZ6, gid, nthr);

    for (int i = gid; i < 4 * 66 * 64; i += nthr) {
        int cb = i / (66 * 64);
        int r = i - cb * (66 * 64);
        int ks = r >> 6, L = r & 63;
        int col = cb * 16 + (L & 15);
        union { short s[8]; bf16x8 v; } w;
        #pragma unroll
        for (int j = 0; j < 8; ++j) {
            int f = ks * 32 + ((L >> 4) << 3) + j;
            float v = (f < NFUNC) ? XI[(size_t)f * DDIM + col] * XIm[(size_t)f * DDIM + col] : 0.f;
            w.s[j] = f2b(v);
        }
        *(bf16x8*)(xiP + (size_t)i * 8) = w.v;
    }

    for (int f = gid; f < NFPAD; f += nthr) {
        int a, b;
        if (f == 0) { a = 64; b = 64; }
        else if (f <= DDIM) { a = f - 1; b = 64; }
        else if (f < NFUNC) {
            int p = f - 1 - DDIM; int i2 = 0, cum = 0;
            while (cum + (63 - i2) <= p) { cum += 63 - i2; ++i2; }
            a = i2; b = i2 + 1 + (p - cum);
        } else { a = 65; b = 65; }
        pk[f] = make_int2(a, b);
    }
}

// =====================================================================
// 256 blocks x 512 threads (8 waves, 2 per SIMD), ONE row-tile per block.
// Wide phases (L1, builds, dec2, dec3) split 8 ways; narrow N=64 phases
// (L2, L3, SINDy-MFMA, dec1) run on waves 0-3 only. All plain loads (r5's
// proven path); numerics identical to r5/r10.
__global__ __launch_bounds__(512, 2)
void fused(const float* __restrict__ be1, const float* __restrict__ be2,
           const float* __restrict__ be3, const float* __restrict__ bd1,
           const float* __restrict__ bd2, const float* __restrict__ bd3,
           const short* __restrict__ Wp1, const short* __restrict__ Wp2,
           const short* __restrict__ Wp3, const short* __restrict__ Wp4,
           const short* __restrict__ Wp5, const short* __restrict__ Wp6,
           const short* __restrict__ xiP, const int2* __restrict__ pk,
           float* __restrict__ xh, float* __restrict__ dxh, float* __restrict__ zo,
           float* __restrict__ dz, float* __restrict__ dzs)
{
    __shared__ __align__(16) char ldsbuf[37120];
    short* h1s0 = (short*)(ldsbuf + 0);
    short* h1s1 = (short*)(ldsbuf + 4096);
    short* h1s2 = (short*)(ldsbuf + 8192);
    short* v1   = (short*)(ldsbuf + 12288);
    short* h2s0 = (short*)(ldsbuf + 16384);
    short* h2s1 = (short*)(ldsbuf + 18432);
    short* h2s2 = (short*)(ldsbuf + 20480);
    short* v2   = (short*)(ldsbuf + 22528);
    short* th   = (short*)(ldsbuf + 0);      // [16][704] swizzled
    short* g1s0 = (short*)(ldsbuf + 0);
    short* g1s1 = (short*)(ldsbuf + 2048);
    short* g1s2 = (short*)(ldsbuf + 4096);
    short* u1   = (short*)(ldsbuf + 6144);
    short* g2s0 = (short*)(ldsbuf + 8192);
    short* g2s1 = (short*)(ldsbuf + 12288);
    short* g2s2 = (short*)(ldsbuf + 16384);
    short* u2   = (short*)(ldsbuf + 20480);
    short* zb0  = (short*)(ldsbuf + 24576);
    short* zb1  = (short*)(ldsbuf + 26624);
    short* zb2  = (short*)(ldsbuf + 28672);
    short* dzsb = (short*)(ldsbuf + 30720);
    float* zf   = (float*)(ldsbuf + 32768);  // [16][68]

    const int tid = threadIdx.x, lane = tid & 63, wave = tid >> 6;
    const int wq = wave & 3;
    const int row0 = blockIdx.x * 16;
    const int c16 = lane & 15;
    const int tr = tid & 15, bg = tid >> 4;     // builder: 32 groups x 16 rows
    const int tf = bg * 22;                     // 22 funcs per builder group

    // ---- bias preload ----
    float bb1 = be1[wave * 16 + c16];
    float bb2 = be2[wq * 16 + c16];
    float bb3 = be3[wq * 16 + c16];
    float bD1 = bd1[wq * 16 + c16];
    float bD2 = bd2[wave * 16 + c16];
    float bD3[4];
    #pragma unroll
    for (int i = 0; i < 4; ++i) bD3[i] = bd3[wave * 64 + i * 16 + c16];

    // ================= encoder L1 (K=512, N=128): 1 col-frag/wave, depth-3 ====
    {
        const short* bx = (const short*)(xh + (size_t)blockIdx.x * 8192);
        const short* bd = (const short*)(dxh + (size_t)blockIdx.x * 8192);
        f32x4 P = {}, Q = {}, V = {};
        bf16x8 A0[3], A1[3], A2[3], Ad[3], B0[3], B1[3], B2[3];
#define L1_LA(ks, sl) { int off = ((ks) * 64 + lane) * 8; \
        A0[sl] = *(const bf16x8*)(bx + off); A1[sl] = *(const bf16x8*)(bx + 8192 + off); \
        A2[sl] = *(const bf16x8*)(bd + off); Ad[sl] = *(const bf16x8*)(bd + 8192 + off); }
#define L1_LB(ks, sl) { int blk = wave * 16 + (ks); \
        B0[sl] = ld_bp(Wp1, blk, lane); B1[sl] = ld_bp(Wp1 + WSZ1, blk, lane); \
        B2[sl] = ld_bp(Wp1 + 2 * WSZ1, blk, lane); }
        L1_LA(0, 0) L1_LB(0, 0)
        L1_LA(1, 1) L1_LB(1, 1)
        L1_LA(2, 2) L1_LB(2, 2)
        #pragma unroll
        for (int ks = 0; ks < 16; ++ks) {
            const int sl = ks % 3;
            mf9(A0[sl], A1[sl], A2[sl], Ad[sl], B0[sl], B1[sl], B2[sl], P, Q, V);
            if (ks + 3 < 16) { L1_LA(ks + 3, sl) L1_LB(ks + 3, sl) }
        }
#undef L1_LA
#undef L1_LB
        epi_store(h1s0, h1s1, h1s2, v1, 128, lane, wave * 16 + c16, P, Q, V, bb1);
    }
    bf16x8 L2B[4][3];
    if (wave < 4) {
        #pragma unroll
        for (int ks = 0; ks < 4; ++ks) {
            int blk = wq * 4 + ks;
            L2B[ks][0] = ld_bp(Wp2, blk, lane);
            L2B[ks][1] = ld_bp(Wp2 + WSZ2, blk, lane);
            L2B[ks][2] = ld_bp(Wp2 + 2 * WSZ2, blk, lane);
        }
    }
    __syncthreads();

    // ================= encoder L2 (K=128, N=64): waves 0-3 ========
    bf16x8 L3B[2][3];
    if (wave < 4) {
        bf16x8 Aa[4][4];
        #pragma unroll
        for (int ks = 0; ks < 4; ++ks) {
            Aa[ks][0] = ld_af(h1s0, 128, lane, ks * 32);
            Aa[ks][1] = ld_af(h1s1, 128, lane, ks * 32);
            Aa[ks][2] = ld_af(h1s2, 128, lane, ks * 32);
            Aa[ks][3] = ld_af(v1, 128, lane, ks * 32);
        }
        #pragma unroll
        for (int ks = 0; ks < 2; ++ks) {
            int blk = wq * 2 + ks;
            L3B[ks][0] = ld_bp(Wp3, blk, lane);
            L3B[ks][1] = ld_bp(Wp3 + WSZ3, blk, lane);
            L3B[ks][2] = ld_bp(Wp3 + 2 * WSZ3, blk, lane);
        }
        f32x4 P = {}, Q = {}, V = {};
        #pragma unroll
        for (int ks = 0; ks < 4; ++ks)
            mf9(Aa[ks][0], Aa[ks][1], Aa[ks][2], Aa[ks][3], L2B[ks][0], L2B[ks][1], L2B[ks][2], P, Q, V);
        epi_store(h2s0, h2s1, h2s2, v2, 64, lane, wq * 16 + c16, P, Q, V, bb2);
    }
    __syncthreads();

    // ================= encoder L3 (K=64) -> z: waves 0-3 ========
    bf16x8 X[KS_PER_CHUNK];
    if (wave < 4) {
        bf16x8 Aa[2][4];
        #pragma unroll
        for (int ks = 0; ks < 2; ++ks) {
            Aa[ks][0] = ld_af(h2s0, 64, lane, ks * 32);
            Aa[ks][1] = ld_af(h2s1, 64, lane, ks * 32);
            Aa[ks][2] = ld_af(h2s2, 64, lane, ks * 32);
            Aa[ks][3] = ld_af(v2, 64, lane, ks * 32);
        }
        f32x4 P = {}, Q = {}, V = {};
        #pragma unroll
        for (int ks = 0; ks < 2; ++ks)
            mf9(Aa[ks][0], Aa[ks][1], Aa[ks][2], Aa[ks][3], L3B[ks][0], L3B[ks][1], L3B[ks][2], P, Q, V);
        #pragma unroll
        for (int kk = 0; kk < KS_PER_CHUNK; ++kk)
            X[kk] = ld_bp(xiP, wq * 66 + kk, lane);
        int col = wq * 16 + c16;
        #pragma unroll
        for (int q = 0; q < 4; ++q) {
            int row = (lane >> 4) * 4 + q;
            float pre = P[q] + Q[q] + bb3;
            float hz = fmaxf(pre, 0.f);
            float vz = pre > 0.f ? V[q] : 0.f;
            zf[row * 68 + col] = hz;
            short s0, s1, s2;
            split3f(hz, s0, s1, s2);
            st_b16(zb0, 64, row, col, s0);
            st_b16(zb1, 64, row, col, s1);
            st_b16(zb2, 64, row, col, s2);
            zo[(size_t)(row0 + row) * DDIM + col] = hz;
            dz[(size_t)(row0 + row) * DDIM + col] = vz;
        }
        if (tid < 32) { int r = tid & 15; zf[r * 68 + 64 + (tid >> 4)] = (tid >> 4) ? 0.f : 1.f; }
    }
    __syncthreads();   // zf/zb ready; h1/h2 dead -> th may overwrite

    // ================= SINDy: builds on 512 threads, MFMA on waves 0-3 ========
    f32x4 sa0 = {}, sa1 = {};
    auto build = [&](int ch) {
        #pragma clang loop unroll(disable)
        for (int j = 0; j < 11; ++j) {
            int f0 = ch * CHUNK + tf + 2 * j;
            int2 p0 = pk[f0], p1 = pk[f0 + 1];
            float t0 = zf[tr * 68 + p0.x] * zf[tr * 68 + p0.y];
            float t1 = zf[tr * 68 + p1.x] * zf[tr * 68 + p1.y];
            unsigned u = (unsigned)(unsigned short)f2b(t0)
                       | ((unsigned)(unsigned short)f2b(t1) << 16);
            st_b32s(th, 704, tr, tf + 2 * j, u);
        }
    };
#define SMF() { _Pragma("unroll") for (int kk = 0; kk < KS_PER_CHUNK; ++kk) { \
        bf16x8 a = ld_af(th, 704, lane, kk * 32); \
        if (kk & 1) sa1 = MFMA(a, X[kk], sa1); else sa0 = MFMA(a, X[kk], sa0); } }
#define ISX(ch) { _Pragma("unroll") for (int kk = 0; kk < KS_PER_CHUNK; ++kk) \
        X[kk] = ld_bp(xiP, wq * 66 + (ch) * KS_PER_CHUNK + kk, lane); }

    build(0);
    __syncthreads();
    if (wave < 4) { SMF() ISX(1) }
    __syncthreads();
    build(1);
    __syncthreads();
    if (wave < 4) { SMF() ISX(2) }
    __syncthreads();
    build(2);
    __syncthreads();
    bf16x8 D1B[2][3];
    if (wave < 4) {
        SMF()
        f32x4 sacc = sa0 + sa1;
        #pragma unroll
        for (int ks = 0; ks < 2; ++ks) {
            int blk = wq * 2 + ks;
            D1B[ks][0] = ld_bp(Wp4, blk, lane);
            D1B[ks][1] = ld_bp(Wp4 + WSZ4, blk, lane);
            D1B[ks][2] = ld_bp(Wp4 + 2 * WSZ4, blk, lane);
        }
        int col = wq * 16 + c16;
        #pragma unroll
        for (int q = 0; q < 4; ++q) {
            int row = (lane >> 4) * 4 + q;
            float v = sacc[q];
            dzs[(size_t)(row0 + row) * DDIM + col] = v;
            st_b16(dzsb, 64, row, col, f2b(v));
        }
    }
#undef SMF
#undef ISX
    __syncthreads();   // dzsb ready; th dead -> g1 may overwrite

    // ================= decoder L1 (K=64): waves 0-3; all waves prefetch D2B ====
    bf16x8 D2B[2][3];
    if (wave < 4) {
        bf16x8 Aa[2][4];
        #pragma unroll
        for (int ks = 0; ks < 2; ++ks) {
            Aa[ks][0] = ld_af(zb0, 64, lane, ks * 32);
            Aa[ks][1] = ld_af(zb1, 64, lane, ks * 32);
            Aa[ks][2] = ld_af(zb2, 64, lane, ks * 32);
            Aa[ks][3] = ld_af(dzsb, 64, lane, ks * 32);
        }
        f32x4 P = {}, Q = {}, V = {};
        #pragma unroll
        for (int ks = 0; ks < 2; ++ks)
            mf9(Aa[ks][0], Aa[ks][1], Aa[ks][2], Aa[ks][3], D1B[ks][0], D1B[ks][1], D1B[ks][2], P, Q, V);
        epi_store(g1s0, g1s1, g1s2, u1, 64, lane, wq * 16 + c16, P, Q, V, bD1);
    }
    #pragma unroll
    for (int ks = 0; ks < 2; ++ks) {       // ALL waves: own dec2 B (N=128, cb=wave)
        int blk = wave * 2 + ks;
        D2B[ks][0] = ld_bp(Wp5, blk, lane);
        D2B[ks][1] = ld_bp(Wp5 + WSZ5, blk, lane);
        D2B[ks][2] = ld_bp(Wp5 + 2 * WSZ5, blk, lane);
    }
    __syncthreads();

    // ================= decoder L2 (K=64, N=128): all 8 waves, 1 frag each ====
    {
        bf16x8 Aa[2][4];
        #pragma unroll
        for (int ks = 0; ks < 2; ++ks) {
            Aa[ks][0] = ld_af(g1s0, 64, lane, ks * 32);
            Aa[ks][1] = ld_af(g1s1, 64, lane, ks * 32);
            Aa[ks][2] = ld_af(g1s2, 64, lane, ks * 32);
            Aa[ks][3] = ld_af(u1, 64, lane, ks * 32);
        }
        f32x4 P = {}, Q = {}, V = {};
        #pragma unroll
        for (int ks = 0; ks < 2; ++ks)
            mf9(Aa[ks][0], Aa[ks][1], Aa[ks][2], Aa[ks][3], D2B[ks][0], D2B[ks][1], D2B[ks][2], P, Q, V);
        epi_store(g2s0, g2s1, g2s2, u2, 128, lane, wave * 16 + c16, P, Q, V, bD2);
    }
    __syncthreads();

    // ================= decoder L3 (K=128, N=512): all 8 waves, 64 cols each ====
    {
        f32x4 P[4] = {}, Q[4] = {}, V[4] = {};
        bf16x8 Bp[4][3];
        bf16x8 Ax0[2], Ax1[2], Ax2[2], Axv[2];
#define D3_LA(ks, b) { Ax0[b] = ld_af(g2s0, 128, lane, (ks) * 32); Ax1[b] = ld_af(g2s1, 128, lane, (ks) * 32); \
                       Ax2[b] = ld_af(g2s2, 128, lane, (ks) * 32); Axv[b] = ld_af(u2, 128, lane, (ks) * 32); }
#define D3_LB(s, sl) { int blk = (wave * 4 + ((s) & 3)) * 4 + ((s) >> 2); \
        Bp[sl][0] = ld_bp(Wp6, blk, lane); Bp[sl][1] = ld_bp(Wp6 + WSZ6, blk, lane); \
        Bp[sl][2] = ld_bp(Wp6 + 2 * WSZ6, blk, lane); }
        D3_LA(0, 0)
        D3_LB(0, 0) D3_LB(1, 1) D3_LB(2, 2) D3_LB(3, 3)
        #pragma unroll
        for (int ks = 0; ks < 4; ++ks) {
            if (ks < 3) D3_LA(ks + 1, (ks + 1) & 1)
            #pragma unroll
            for (int cf = 0; cf < 4; ++cf) {
                const int s = ks * 4 + cf, sl = s & 3;
                mf9(Ax0[ks & 1], Ax1[ks & 1], Ax2[ks & 1], Axv[ks & 1],
                    Bp[sl][0], Bp[sl][1], Bp[sl][2], P[cf], Q[cf], V[cf]);
                if (s + 4 < 16) D3_LB(s + 4, sl)
            }
        }
#undef D3_LA
#undef D3_LB
        #pragma unroll
        for (int cf = 0; cf < 4; ++cf) {
            int col = wave * 64 + cf * 16 + c16;
            float bb = bD3[cf];
            #pragma unroll
            for (int q = 0; q < 4; ++q) {
                int row = (lane >> 4) * 4 + q;
                float pre = P[cf][q] + Q[cf][q] + bb;
                xh[(size_t)(row0 + row) * IN_DIM + col] = fmaxf(pre, 0.f);
                dxh[(size_t)(row0 + row) * IN_DIM + col] = pre > 0.f ? V[cf][q] : 0.f;
            }
        }
    }
}

// =====================================================================
extern "C" void kernel_launch(void* const* d_in, const int* in_sizes, int n_in,
                              void* d_out, int out_size, void* d_ws, size_t ws_size,
                              hipStream_t stream)
{
    const float* x    = (const float*)d_in[0];
    const float* xdot = (const float*)d_in[1];
    const float* We1  = (const float*)d_in[2];
    const float* be1  = (const float*)d_in[3];
    const float* We2  = (const float*)d_in[4];
    const float* be2  = (const float*)d_in[5];
    const float* We3  = (const float*)d_in[6];
    const float* be3  = (const float*)d_in[7];
    const float* Wd1  = (const float*)d_in[8];
    const float* bd1  = (const float*)d_in[9];
    const float* Wd2  = (const float*)d_in[10];
    const float* bd2  = (const float*)d_in[11];
    const float* Wd3  = (const float*)d_in[12];
    const float* bd3  = (const float*)d_in[13];
    const float* XI   = (const float*)d_in[14];
    const float* XIm  = (const float*)d_in[15];

    float* out = (float*)d_out;
    float* xh  = out;
    float* dxh = out + (size_t)BATCH * IN_DIM;
    float* zo  = dxh + (size_t)BATCH * IN_DIM;
    float* dz  = zo + (size_t)BATCH * DDIM;
    float* dzs = dz + (size_t)BATCH * DDIM;

    int2*  pk  = (int2*)d_ws;
    short* Wp1 = (short*)(pk + NFPAD);
    short* Wp2 = Wp1 + 3 * WSZ1;
    short* Wp3 = Wp2 + 3 * WSZ2;
    short* Wp4 = Wp3 + 3 * WSZ3;
    short* Wp5 = Wp4 + 3 * WSZ4;
    short* Wp6 = Wp5 + 3 * WSZ5;
    short* xiP = Wp6 + 3 * WSZ6;

    initk<<<1024, 256, 0, stream>>>(x, xdot, We1, We2, We3, Wd1, Wd2, Wd3, XI, XIm,
                                    xh, dxh, Wp1, Wp2, Wp3, Wp4, Wp5, Wp6, xiP, pk);
    fused<<<BATCH / 16, 512, 0, stream>>>(be1, be2, be3, bd1, bd2, bd3,
                                          Wp1, Wp2, Wp3, Wp4, Wp5, Wp6, xiP, pk,
                                          xh, dxh, zo, dz, dzs);
}